// Round 1
// baseline (1397.962 us; speedup 1.0000x reference)
//
#include <hip/hip_runtime.h>
#include <math.h>

// ---------------- constants ----------------
#define NIMG   2048   // B*S
#define BATCH  64
#define SEQ    32

__device__ __forceinline__ float siluf(float v) { return v / (1.0f + expf(-v)); }
__device__ __forceinline__ float reluf(float v) { return v > 0.0f ? v : 0.0f; }
__device__ __forceinline__ float softplusf(float x) {
    // stable log1p(exp(x))
    return x > 0.0f ? x + log1pf(expf(-x)) : log1pf(expf(x));
}

// ---------------- conv1: (2048,4,84,84)/255 -> (2048,32,20,20), k=8 s=4, relu ----
// grid 2048, block 128. thread tile 4oc x 5ox. 5 chunks of 4 output rows.
__global__ __launch_bounds__(128) void k_conv1(const float* __restrict__ x,
                                               const float* __restrict__ w,
                                               const float* __restrict__ bias,
                                               float* __restrict__ out) {
    __shared__ float s_in[4][20][84];   // 26.88 KB
    const int tid = threadIdx.x;
    const int img = blockIdx.x;
    const float* __restrict__ xin = x + (size_t)img * (4 * 84 * 84);

    const int ocg  = tid >> 4;      // 0..7  (4 oc each)
    const int rem  = tid & 15;
    const int oy_l = rem >> 2;      // 0..3
    const int oxg  = rem & 3;       // 0..3  (5 ox each)
    const int oc0  = ocg * 4;
    const int ox0  = oxg * 5;
    const int iy0  = oy_l * 4;

    float b0 = bias[oc0], b1 = bias[oc0 + 1], b2 = bias[oc0 + 2], b3 = bias[oc0 + 3];

    for (int chunk = 0; chunk < 5; ++chunk) {
        __syncthreads();
        const int row0 = chunk * 16;
        for (int i = tid; i < 4 * 20 * 84; i += 128) {
            int c = i / 1680, r = (i % 1680) / 84, col = i % 84;
            s_in[c][r][col] = xin[(size_t)(c * 84 + row0 + r) * 84 + col] * (1.0f / 255.0f);
        }
        __syncthreads();

        float acc[4][5];
        #pragma unroll
        for (int o = 0; o < 4; ++o)
            #pragma unroll
            for (int j = 0; j < 5; ++j) acc[o][j] = 0.0f;

        for (int ic = 0; ic < 4; ++ic) {
            #pragma unroll
            for (int ky = 0; ky < 8; ++ky) {
                const float* irow = &s_in[ic][iy0 + ky][0];
                float4 wa[4], wb[4];
                #pragma unroll
                for (int o = 0; o < 4; ++o) {
                    const float* wp = w + ((size_t)(oc0 + o) * 4 + ic) * 64 + ky * 8;
                    wa[o] = *(const float4*)wp;
                    wb[o] = *(const float4*)(wp + 4);
                }
                #pragma unroll
                for (int j = 0; j < 5; ++j) {
                    const float* ip = irow + (ox0 + j) * 4;
                    float4 ia = *(const float4*)ip;
                    float4 ib = *(const float4*)(ip + 4);
                    #pragma unroll
                    for (int o = 0; o < 4; ++o) {
                        acc[o][j] += wa[o].x * ia.x + wa[o].y * ia.y + wa[o].z * ia.z + wa[o].w * ia.w
                                   + wb[o].x * ib.x + wb[o].y * ib.y + wb[o].z * ib.z + wb[o].w * ib.w;
                    }
                }
            }
        }

        const int oy = chunk * 4 + oy_l;
        float bb[4] = {b0, b1, b2, b3};
        #pragma unroll
        for (int o = 0; o < 4; ++o)
            #pragma unroll
            for (int j = 0; j < 5; ++j)
                out[((size_t)img * 32 + oc0 + o) * 400 + oy * 20 + ox0 + j] = reluf(acc[o][j] + bb[o]);
    }
}

// ---------------- conv2: (2048,32,20,20) -> (2048,64,9,9), k=4 s=2, relu ----
// grid 2048, block 320 (288 active). thread tile 2oc x 9ox.
__global__ __launch_bounds__(320) void k_conv2(const float* __restrict__ in,
                                               const float* __restrict__ w,
                                               const float* __restrict__ bias,
                                               float* __restrict__ out) {
    __shared__ float s_in[32][20][20];  // 51.2 KB
    const int tid = threadIdx.x;
    const int img = blockIdx.x;
    const float* __restrict__ src = in + (size_t)img * 12800;
    for (int i = tid; i < 3200; i += 320) ((float4*)s_in)[i] = ((const float4*)src)[i];
    __syncthreads();

    if (tid < 288) {
        const int ocg = tid / 9, oy = tid % 9;
        const int oc0 = ocg * 2;
        float acc0[9], acc1[9];
        #pragma unroll
        for (int j = 0; j < 9; ++j) { acc0[j] = 0.0f; acc1[j] = 0.0f; }

        for (int ic = 0; ic < 32; ++ic) {
            #pragma unroll
            for (int ky = 0; ky < 4; ++ky) {
                const float* irow = &s_in[ic][2 * oy + ky][0];
                float4 r0 = *(const float4*)(irow);
                float4 r1 = *(const float4*)(irow + 4);
                float4 r2 = *(const float4*)(irow + 8);
                float4 r3 = *(const float4*)(irow + 12);
                float4 r4 = *(const float4*)(irow + 16);
                float xr[20] = {r0.x, r0.y, r0.z, r0.w, r1.x, r1.y, r1.z, r1.w,
                                r2.x, r2.y, r2.z, r2.w, r3.x, r3.y, r3.z, r3.w,
                                r4.x, r4.y, r4.z, r4.w};
                const float* wp0 = w + ((size_t)oc0 * 32 + ic) * 16 + ky * 4;
                float4 w0 = *(const float4*)wp0;
                float4 w1 = *(const float4*)(wp0 + 32 * 16);
                #pragma unroll
                for (int ox = 0; ox < 9; ++ox) {
                    float i0 = xr[2 * ox], i1 = xr[2 * ox + 1], i2 = xr[2 * ox + 2], i3 = xr[2 * ox + 3];
                    acc0[ox] += w0.x * i0 + w0.y * i1 + w0.z * i2 + w0.w * i3;
                    acc1[ox] += w1.x * i0 + w1.y * i1 + w1.z * i2 + w1.w * i3;
                }
            }
        }
        float bb0 = bias[oc0], bb1 = bias[oc0 + 1];
        #pragma unroll
        for (int ox = 0; ox < 9; ++ox) {
            out[((size_t)img * 64 + oc0) * 81 + oy * 9 + ox]     = reluf(acc0[ox] + bb0);
            out[((size_t)img * 64 + oc0 + 1) * 81 + oy * 9 + ox] = reluf(acc1[ox] + bb1);
        }
    }
}

// ---------------- conv3: (2048,64,9,9) -> (2048,64,7,7) flat (2048,3136), k=3 s=1, relu ----
// grid 2048, block 256 (224 active). thread tile 2oc x 7ox.
__global__ __launch_bounds__(256) void k_conv3(const float* __restrict__ in,
                                               const float* __restrict__ w,
                                               const float* __restrict__ bias,
                                               float* __restrict__ out) {
    __shared__ float s_in[64][81];   // 20.7 KB
    const int tid = threadIdx.x;
    const int img = blockIdx.x;
    const float* __restrict__ src = in + (size_t)img * 5184;
    for (int i = tid; i < 1296; i += 256) ((float4*)s_in)[i] = ((const float4*)src)[i];
    __syncthreads();

    if (tid < 224) {
        const int ocg = tid / 7, oy = tid % 7;
        const int oc0 = ocg * 2;
        float acc0[7], acc1[7];
        #pragma unroll
        for (int j = 0; j < 7; ++j) { acc0[j] = 0.0f; acc1[j] = 0.0f; }

        for (int ic = 0; ic < 64; ++ic) {
            #pragma unroll
            for (int ky = 0; ky < 3; ++ky) {
                const float* irow = &s_in[ic][(oy + ky) * 9];
                float xr[9];
                #pragma unroll
                for (int t = 0; t < 9; ++t) xr[t] = irow[t];
                const float* wp0 = w + ((size_t)oc0 * 64 + ic) * 9 + ky * 3;
                const float* wp1 = wp0 + 64 * 9;
                float w00 = wp0[0], w01 = wp0[1], w02 = wp0[2];
                float w10 = wp1[0], w11 = wp1[1], w12 = wp1[2];
                #pragma unroll
                for (int ox = 0; ox < 7; ++ox) {
                    acc0[ox] += w00 * xr[ox] + w01 * xr[ox + 1] + w02 * xr[ox + 2];
                    acc1[ox] += w10 * xr[ox] + w11 * xr[ox + 1] + w12 * xr[ox + 2];
                }
            }
        }
        float bb0 = bias[oc0], bb1 = bias[oc0 + 1];
        #pragma unroll
        for (int ox = 0; ox < 7; ++ox) {
            out[(size_t)img * 3136 + oc0 * 49 + oy * 7 + ox]       = reluf(acc0[ox] + bb0);
            out[(size_t)img * 3136 + (oc0 + 1) * 49 + oy * 7 + ox] = reluf(acc1[ox] + bb1);
        }
    }
}

// ---------------- generic fp32 GEMM: C[M,N] (+= none) = A[M,K] @ W[N,K]^T ----
// grid (M/64, ceil(N/64), Z), block 256, tile 64x64, thread 4x4, k-chunk 16.
// If Z>1, writes partial into C + z*M*N (no bias). No bias/activation here.
__global__ __launch_bounds__(256) void k_gemm(const float* __restrict__ A,
                                              const float* __restrict__ W,
                                              float* __restrict__ C,
                                              int M, int N, int K, int kpz) {
    __shared__ float As[16][68];
    __shared__ float Ws[16][68];
    const int tid = threadIdx.x;
    const int m0 = blockIdx.x * 64, n0 = blockIdx.y * 64;
    const int k0 = blockIdx.z * kpz;
    const int lr = tid >> 4, lc = tid & 15;   // load decomposition
    const int tm = tid >> 4, tn = tid & 15;   // compute decomposition

    float acc[4][4];
    #pragma unroll
    for (int i = 0; i < 4; ++i)
        #pragma unroll
        for (int j = 0; j < 4; ++j) acc[i][j] = 0.0f;

    for (int kc = 0; kc < kpz; kc += 16) {
        const int kb = k0 + kc + lc;
        __syncthreads();
        #pragma unroll
        for (int i = 0; i < 4; ++i) {
            int r = lr + 16 * i;
            As[lc][r] = A[(size_t)(m0 + r) * K + kb];
            int wr = n0 + r;
            Ws[lc][r] = (wr < N) ? W[(size_t)wr * K + kb] : 0.0f;
        }
        __syncthreads();
        #pragma unroll
        for (int kk = 0; kk < 16; ++kk) {
            float4 a = *(const float4*)&As[kk][tm * 4];
            float4 b = *(const float4*)&Ws[kk][tn * 4];
            acc[0][0] += a.x * b.x; acc[0][1] += a.x * b.y; acc[0][2] += a.x * b.z; acc[0][3] += a.x * b.w;
            acc[1][0] += a.y * b.x; acc[1][1] += a.y * b.y; acc[1][2] += a.y * b.z; acc[1][3] += a.y * b.w;
            acc[2][0] += a.z * b.x; acc[2][1] += a.z * b.y; acc[2][2] += a.z * b.z; acc[2][3] += a.z * b.w;
            acc[3][0] += a.w * b.x; acc[3][1] += a.w * b.y; acc[3][2] += a.w * b.z; acc[3][3] += a.w * b.w;
        }
    }

    float* Cz = C + (size_t)blockIdx.z * M * N;
    #pragma unroll
    for (int i = 0; i < 4; ++i) {
        int m = m0 + tm * 4 + i;
        #pragma unroll
        for (int j = 0; j < 4; ++j) {
            int n = n0 + tn * 4 + j;
            if (n < N) Cz[(size_t)m * N + n] = acc[i][j];
        }
    }
}

// ---------------- reduce 7 K-split partials + bias (feat layer, linear) ----
__global__ __launch_bounds__(256) void k_reduce7(const float* __restrict__ P,
                                                 const float* __restrict__ bias,
                                                 float* __restrict__ out) {
    int idx = blockIdx.x * 256 + threadIdx.x;   // < 2048*128
    int n = idx & 127;
    float s = bias[n];
    #pragma unroll
    for (int z = 0; z < 7; ++z) s += P[(size_t)z * 2048 * 128 + idx];
    out[idx] = s;
}

// ---------------- depthwise causal conv1d (k=4) + bias + silu ----
// grid (64,4): batch x 8-step groups; block 256 = channels.
__global__ __launch_bounds__(256) void k_conv1d(const float* __restrict__ xz,
                                                const float* __restrict__ w,
                                                const float* __restrict__ bias,
                                                float* __restrict__ u) {
    const int b = blockIdx.x, sg = blockIdx.y;
    const int d = threadIdx.x;
    const float w0 = w[d * 4], w1 = w[d * 4 + 1], w2 = w[d * 4 + 2], w3 = w[d * 4 + 3];
    const float bb = bias[d];
    const int s0 = sg * 8;
    float p1 = 0.0f, p2 = 0.0f, p3 = 0.0f;
    int sstart = (sg == 0) ? 0 : s0 - 3;
    for (int s = sstart; s < s0 + 8; ++s) {
        float cur = xz[(size_t)(b * 32 + s) * 512 + d];
        if (s >= s0) {
            float v = w0 * p3 + w1 * p2 + w2 * p1 + w3 * cur + bb;
            u[(size_t)(b * 32 + s) * 256 + d] = siluf(v);
        }
        p3 = p2; p2 = p1; p1 = cur;
    }
}

// ---------------- dt = softplus(x_dbl[:, :8] @ dt_proj_w^T + dt_proj_b) ----
// grid 2048 (rows), block 256 (channels).
__global__ __launch_bounds__(256) void k_dtproj(const float* __restrict__ xdbl,
                                                const float* __restrict__ w,
                                                const float* __restrict__ bias,
                                                float* __restrict__ dt) {
    const int row = blockIdx.x;
    const int j = threadIdx.x;
    float r[8];
    #pragma unroll
    for (int k = 0; k < 8; ++k) r[k] = xdbl[(size_t)row * 72 + k];
    float acc = bias[j];
    #pragma unroll
    for (int k = 0; k < 8; ++k) acc += r[k] * w[j * 8 + k];
    dt[(size_t)row * 256 + j] = softplusf(acc);
}

// ---------------- selective scan; only final-timestep output needed ----
// grid 2048 (= 64 b x 32 d-groups of 8), block 256 (4 waves, 2 channels/wave).
__global__ __launch_bounds__(256) void k_scan(const float* __restrict__ xdbl,
                                              const float* __restrict__ dt,
                                              const float* __restrict__ u,
                                              const float* __restrict__ A_log,
                                              const float* __restrict__ Dv,
                                              const float* __restrict__ xz,
                                              float* __restrict__ ylast) {
    const int blk = blockIdx.x;
    const int b = blk >> 5, dg = blk & 31;
    const int lane = threadIdx.x & 63;
    const int wv = threadIdx.x >> 6;
    const int n = lane & 31;
    const int d = dg * 8 + wv * 2 + (lane >> 5);

    const float A = -expf(A_log[d * 32 + n]);
    float h = 0.0f;
    const size_t rowbase = (size_t)b * 32;
    for (int s = 0; s < 32; ++s) {
        size_t r = rowbase + s;
        float dtv = dt[r * 256 + d];
        float Bn  = xdbl[r * 72 + 8 + n];
        float uv  = u[r * 256 + d];
        float dA  = expf(dtv * A);
        h = dA * h + dtv * Bn * uv;
    }
    size_t r31 = rowbase + 31;
    float yv = h * xdbl[r31 * 72 + 40 + n];
    #pragma unroll
    for (int off = 16; off > 0; off >>= 1) yv += __shfl_xor(yv, off);
    if (n == 0) {
        float uv31 = u[r31 * 256 + d];
        float y = yv + Dv[d] * uv31;
        float z = xz[r31 * 512 + 256 + d];
        ylast[b * 256 + d] = y * siluf(z);
    }
}

// ---------------- head: out_proj -> latent ; fc1 relu ; fc2 relu ; q ----
// grid 64 (batch), block 128.
__global__ __launch_bounds__(128) void k_head(const float* __restrict__ ylast,
                                              const float* __restrict__ op_w,
                                              const float* __restrict__ fc1_w,
                                              const float* __restrict__ fc1_b,
                                              const float* __restrict__ fc2_w,
                                              const float* __restrict__ fc2_b,
                                              const float* __restrict__ q_w,
                                              const float* __restrict__ q_b,
                                              float* __restrict__ out) {
    __shared__ float s_y[256];
    __shared__ float s_l[128];
    __shared__ float s_h1[128];
    __shared__ float s_h2[128];
    const int b = blockIdx.x;
    const int j = threadIdx.x;
    s_y[j]       = ylast[b * 256 + j];
    s_y[j + 128] = ylast[b * 256 + 128 + j];
    __syncthreads();

    // latent = y @ out_proj^T  (no bias)
    {
        float acc = 0.0f;
        const float* wr = op_w + (size_t)j * 256;
        for (int k = 0; k < 256; k += 4) {
            float4 wv = *(const float4*)(wr + k);
            acc += wv.x * s_y[k] + wv.y * s_y[k + 1] + wv.z * s_y[k + 2] + wv.w * s_y[k + 3];
        }
        s_l[j] = acc;
        out[1152 + b * 128 + j] = acc;   // latent output
    }
    __syncthreads();
    {
        float acc = fc1_b[j];
        const float* wr = fc1_w + (size_t)j * 128;
        for (int k = 0; k < 128; k += 4) {
            float4 wv = *(const float4*)(wr + k);
            acc += wv.x * s_l[k] + wv.y * s_l[k + 1] + wv.z * s_l[k + 2] + wv.w * s_l[k + 3];
        }
        s_h1[j] = reluf(acc);
    }
    __syncthreads();
    {
        float acc = fc2_b[j];
        const float* wr = fc2_w + (size_t)j * 128;
        for (int k = 0; k < 128; k += 4) {
            float4 wv = *(const float4*)(wr + k);
            acc += wv.x * s_h1[k] + wv.y * s_h1[k + 1] + wv.z * s_h1[k + 2] + wv.w * s_h1[k + 3];
        }
        s_h2[j] = reluf(acc);
    }
    __syncthreads();
    if (j < 18) {
        float acc = q_b[j];
        const float* wr = q_w + (size_t)j * 128;
        for (int k = 0; k < 128; k += 4) {
            float4 wv = *(const float4*)(wr + k);
            acc += wv.x * s_h2[k] + wv.y * s_h2[k + 1] + wv.z * s_h2[k + 2] + wv.w * s_h2[k + 3];
        }
        out[b * 18 + j] = acc;   // q output
    }
}

// ---------------- launch ----------------
extern "C" void kernel_launch(void* const* d_in, const int* in_sizes, int n_in,
                              void* d_out, int out_size, void* d_ws, size_t ws_size,
                              hipStream_t stream) {
    const float* x        = (const float*)d_in[0];
    const float* conv1_w  = (const float*)d_in[1];
    const float* conv1_b  = (const float*)d_in[2];
    const float* conv2_w  = (const float*)d_in[3];
    const float* conv2_b  = (const float*)d_in[4];
    const float* conv3_w  = (const float*)d_in[5];
    const float* conv3_b  = (const float*)d_in[6];
    const float* feat_w   = (const float*)d_in[7];
    const float* feat_b   = (const float*)d_in[8];
    const float* in_proj_w = (const float*)d_in[9];
    const float* conv1d_w = (const float*)d_in[10];
    const float* conv1d_b = (const float*)d_in[11];
    const float* x_proj_w = (const float*)d_in[12];
    const float* dt_proj_w = (const float*)d_in[13];
    const float* dt_proj_b = (const float*)d_in[14];
    const float* A_log    = (const float*)d_in[15];
    const float* Dvec     = (const float*)d_in[16];
    const float* out_proj_w = (const float*)d_in[17];
    const float* fc1_w    = (const float*)d_in[18];
    const float* fc1_b    = (const float*)d_in[19];
    const float* fc2_w    = (const float*)d_in[20];
    const float* fc2_b    = (const float*)d_in[21];
    const float* q_w      = (const float*)d_in[22];
    const float* q_b      = (const float*)d_in[23];
    float* out = (float*)d_out;

    // workspace layout (floats)
    float* ws = (float*)d_ws;
    float* c1    = ws;                    // 26,214,400  (2048*32*400)
    float* c2    = ws + 26214400;         // 10,616,832  (2048*64*81)
    float* c3    = ws;                    // 6,422,528   (2048*3136)  reuses c1 region
    float* featP = ws + 6422528;          // 7*2048*128 = 1,835,008
    float* feat  = ws + 8257536;          // 262,144
    float* xz    = ws + 8519680;          // 1,048,576
    float* u     = ws + 9568256;          // 524,288
    float* xdbl  = ws + 10092544;         // 147,456
    float* dt    = ws + 10240000;         // 524,288
    float* ylast = ws + 10764288;         // 16,384

    k_conv1<<<dim3(NIMG), dim3(128), 0, stream>>>(x, conv1_w, conv1_b, c1);
    k_conv2<<<dim3(NIMG), dim3(320), 0, stream>>>(c1, conv2_w, conv2_b, c2);
    k_conv3<<<dim3(NIMG), dim3(256), 0, stream>>>(c2, conv3_w, conv3_b, c3);

    // feat = h @ feat_w^T + feat_b   (K-split 7, then reduce+bias)
    k_gemm<<<dim3(32, 2, 7), dim3(256), 0, stream>>>(c3, feat_w, featP, 2048, 128, 3136, 448);
    k_reduce7<<<dim3(1024), dim3(256), 0, stream>>>(featP, feat_b, feat);

    // xz = feat @ in_proj_w^T  (2048 x 512)
    k_gemm<<<dim3(32, 8, 1), dim3(256), 0, stream>>>(feat, in_proj_w, xz, 2048, 512, 128, 128);

    // u = silu(causal_conv1d(xz[:, :256]) + b)
    k_conv1d<<<dim3(64, 4), dim3(256), 0, stream>>>(xz, conv1d_w, conv1d_b, u);

    // x_dbl = u @ x_proj_w^T  (2048 x 72)
    k_gemm<<<dim3(32, 2, 1), dim3(256), 0, stream>>>(u, x_proj_w, xdbl, 2048, 72, 256, 256);

    // dt = softplus(x_dbl[:, :8] @ dt_proj_w^T + dt_proj_b)
    k_dtproj<<<dim3(2048), dim3(256), 0, stream>>>(xdbl, dt_proj_w, dt_proj_b, dt);

    // selective scan -> y at final timestep, gated by silu(z)
    k_scan<<<dim3(2048), dim3(256), 0, stream>>>(xdbl, dt, u, A_log, Dvec, xz, ylast);

    // head: latent + q
    k_head<<<dim3(64), dim3(128), 0, stream>>>(ylast, out_proj_w, fc1_w, fc1_b,
                                               fc2_w, fc2_b, q_w, q_b, out);
}